// Round 2
// baseline (364.278 us; speedup 1.0000x reference)
//
#include <hip/hip_runtime.h>

// Butterfly module: gather -> 4 rotation layers -> bias+smooth-ReLU on
// offsets 0..7 of each 16-block -> 4 rotation layers -> scatter.
// Memory-bound streaming op. Round 2 changes:
//  - each block owns a 16-row stripe and streams contiguously along columns
//    (grid-stride), instead of scattering blocks across all rows
//  - non-temporal stores so the 134 MB output stream does not evict the
//    LLC-resident input (FETCH_SIZE was already half-absorbed by L3)
//  - LDS/trig/index setup amortized over multiple column tiles

constexpr int COL_BLOCK = 16;
constexpr int TPB = 256;           // threads per block
constexpr int CPT = 4;             // columns per thread (float4)
constexpr int NSPLIT = 4;          // column splits per 16-row stripe
constexpr float CURV2 = 0.1f * 0.1f;

typedef float floatx4 __attribute__((ext_vector_type(4)));

template <int L>
__device__ __forceinline__ void rot_layer(floatx4 (&x)[16],
                                          const float (&cs)[8][8],
                                          const float (&sn)[8][8]) {
    constexpr int b = L & 3;
    constexpr int s = 1 << b;
#pragma unroll
    for (int j = 0; j < 8; ++j) {
        const int lo = ((j >> b) << (b + 1)) | (j & (s - 1));
        const int hi = lo + s;
        const float c = cs[L][j];
        const float sv = sn[L][j];
        const floatx4 xl = x[lo];
        const floatx4 xh = x[hi];
        x[lo] = c * xl + sv * xh;
        x[hi] = c * xh - sv * xl;
    }
}

__global__ __launch_bounds__(TPB) void butterfly_kernel(
    const float* __restrict__ data,     // [N, B]
    const float* __restrict__ angles,   // [8, N/2]
    const float* __restrict__ biases,   // [8 * N/16]
    const int* __restrict__ indices_in, // [N]
    const int* __restrict__ idx_out,    // [N]
    float* __restrict__ out,            // [N, B]
    int N, int B)
{
    const int split = blockIdx.x;        // column split (fast-varying)
    const int blk = blockIdx.y;          // 16-row block index
    const int tid = threadIdx.x;
    const int half = N >> 1;

    __shared__ float cs[8][8];
    __shared__ float sn[8][8];
    __shared__ float bs[8];
    __shared__ int rin[16];
    __shared__ int rout[16];

    if (tid < 64) {
        const int l = tid >> 3, j = tid & 7;
        const float a = angles[l * half + blk * 8 + j];
        cs[l][j] = cosf(a);
        sn[l][j] = sinf(a);
    } else if (tid < 72) {
        bs[tid - 64] = biases[blk * 8 + (tid - 64)];
    } else if (tid < 88) {
        rin[tid - 72] = indices_in[blk * 16 + (tid - 72)];
    } else if (tid < 104) {
        rout[tid - 88] = idx_out[blk * 16 + (tid - 88)];
    }
    __syncthreads();

    const int span = B / NSPLIT;         // contiguous column span per block
    const int cbeg = split * span;
    const int cend = cbeg + span;

    for (int c0 = cbeg + tid * CPT; c0 < cend; c0 += TPB * CPT) {
        floatx4 x[16];
#pragma unroll
        for (int j = 0; j < 16; ++j) {
            const size_t off = (size_t)rin[j] * (size_t)B + (size_t)c0;
            x[j] = *reinterpret_cast<const floatx4*>(data + off);
        }

        rot_layer<0>(x, cs, sn);   // stride 1
        rot_layer<1>(x, cs, sn);   // stride 2
        rot_layer<2>(x, cs, sn);   // stride 4
        rot_layer<3>(x, cs, sn);   // stride 8

        // bias + smooth ReLU on offsets 0..7
#pragma unroll
        for (int j = 0; j < 8; ++j) {
            const float b = bs[j];
            floatx4 v = x[j];
#pragma unroll
            for (int e = 0; e < 4; ++e) {
                const float a = v[e] + b;
                v[e] = 0.5f * (a + sqrtf(fmaf(a, a, CURV2)));
            }
            x[j] = v;
        }

        rot_layer<4>(x, cs, sn);   // stride 1
        rot_layer<5>(x, cs, sn);   // stride 2
        rot_layer<6>(x, cs, sn);   // stride 4
        rot_layer<7>(x, cs, sn);   // stride 8

#pragma unroll
        for (int j = 0; j < 16; ++j) {
            const size_t off = (size_t)rout[j] * (size_t)B + (size_t)c0;
            __builtin_nontemporal_store(x[j], reinterpret_cast<floatx4*>(out + off));
        }
    }
}

// mark rows covered by idx_out
__global__ void mark_kernel(const int* __restrict__ idx_out,
                            int* __restrict__ mask, int N) {
    const int i = blockIdx.x * blockDim.x + threadIdx.x;
    if (i < N) mask[idx_out[i]] = 1;
}

// copy rows NOT covered by idx_out straight from data (out = data elsewhere)
__global__ __launch_bounds__(TPB) void copy_untouched(
    const float* __restrict__ data, float* __restrict__ out,
    const int* __restrict__ mask, int N, int B) {
    for (int row = blockIdx.x; row < N; row += gridDim.x) {
        if (mask[row]) continue;
        const floatx4* src = reinterpret_cast<const floatx4*>(data + (size_t)row * B);
        floatx4* dst = reinterpret_cast<floatx4*>(out + (size_t)row * B);
        for (int c = threadIdx.x; c < (B >> 2); c += blockDim.x)
            __builtin_nontemporal_store(src[c], dst + c);
    }
}

extern "C" void kernel_launch(void* const* d_in, const int* in_sizes, int n_in,
                              void* d_out, int out_size, void* d_ws, size_t ws_size,
                              hipStream_t stream) {
    const float* data       = (const float*)d_in[0];
    const float* angles     = (const float*)d_in[1];
    const float* biases     = (const float*)d_in[2];
    const int*   indices_in = (const int*)d_in[3];
    const int*   idx_out    = (const int*)d_in[4];
    float* out = (float*)d_out;

    const int N = in_sizes[3];          // 4096
    const int B = in_sizes[0] / N;      // 8192

    int* mask = (int*)d_ws;
    hipMemsetAsync(mask, 0, (size_t)N * sizeof(int), stream);
    mark_kernel<<<dim3((N + TPB - 1) / TPB), dim3(TPB), 0, stream>>>(idx_out, mask, N);

    dim3 grid(NSPLIT, N / COL_BLOCK);
    butterfly_kernel<<<grid, dim3(TPB), 0, stream>>>(
        data, angles, biases, indices_in, idx_out, out, N, B);

    copy_untouched<<<dim3(256), dim3(TPB), 0, stream>>>(data, out, mask, N, B);
}

// Round 3
// 247.867 us; speedup vs baseline: 1.4697x; 1.4697x over previous
//
#include <hip/hip_runtime.h>

// Butterfly module: gather -> 4 rotation layers -> bias+smooth-ReLU on
// offsets 0..7 of each 16-block -> 4 rotation layers -> scatter.
// Round 3: revert round-2 regressions (nt stores caused 2.5x write
// amplification + LLC thrash; grid-stride loop blew VGPRs to 256).
// Keep round-1 structure, but swap grid order so the column tile is the
// fast-varying block dimension: concurrently-resident blocks then cover
// contiguous 512 KB row-block stripes instead of scattered 4 KB chunks,
// improving DRAM row-buffer locality.

constexpr int COL_BLOCK = 16;
constexpr int TPB = 256;           // threads per block
constexpr int CPT = 4;             // columns per thread (float4)
constexpr float CURV2 = 0.1f * 0.1f;

typedef float floatx4 __attribute__((ext_vector_type(4)));

template <int L>
__device__ __forceinline__ void rot_layer(floatx4 (&x)[16],
                                          const float (&cs)[8][8],
                                          const float (&sn)[8][8]) {
    constexpr int b = L & 3;
    constexpr int s = 1 << b;
#pragma unroll
    for (int j = 0; j < 8; ++j) {
        const int lo = ((j >> b) << (b + 1)) | (j & (s - 1));
        const int hi = lo + s;
        const float c = cs[L][j];
        const float sv = sn[L][j];
        const floatx4 xl = x[lo];
        const floatx4 xh = x[hi];
        x[lo] = c * xl + sv * xh;
        x[hi] = c * xh - sv * xl;
    }
}

__global__ __launch_bounds__(TPB) void butterfly_kernel(
    const float* __restrict__ data,     // [N, B]
    const float* __restrict__ angles,   // [8, N/2]
    const float* __restrict__ biases,   // [8 * N/16]
    const int* __restrict__ indices_in, // [N]
    const int* __restrict__ idx_out,    // [N]
    float* __restrict__ out,            // [N, B]
    int N, int B)
{
    const int tile = blockIdx.x;         // column tile (fast-varying)
    const int blk = blockIdx.y;          // 16-row block index
    const int tid = threadIdx.x;
    const int half = N >> 1;

    __shared__ float cs[8][8];
    __shared__ float sn[8][8];
    __shared__ float bs[8];
    __shared__ int rin[16];
    __shared__ int rout[16];

    if (tid < 64) {
        const int l = tid >> 3, j = tid & 7;
        const float a = angles[l * half + blk * 8 + j];
        cs[l][j] = cosf(a);
        sn[l][j] = sinf(a);
    } else if (tid < 72) {
        bs[tid - 64] = biases[blk * 8 + (tid - 64)];
    } else if (tid < 88) {
        rin[tid - 72] = indices_in[blk * 16 + (tid - 72)];
    } else if (tid < 104) {
        rout[tid - 88] = idx_out[blk * 16 + (tid - 88)];
    }
    __syncthreads();

    const int c0 = tile * (TPB * CPT) + tid * CPT;

    floatx4 x[16];
#pragma unroll
    for (int j = 0; j < 16; ++j) {
        const size_t off = (size_t)rin[j] * (size_t)B + (size_t)c0;
        x[j] = *reinterpret_cast<const floatx4*>(data + off);
    }

    rot_layer<0>(x, cs, sn);   // stride 1
    rot_layer<1>(x, cs, sn);   // stride 2
    rot_layer<2>(x, cs, sn);   // stride 4
    rot_layer<3>(x, cs, sn);   // stride 8

    // bias + smooth ReLU on offsets 0..7
#pragma unroll
    for (int j = 0; j < 8; ++j) {
        const float b = bs[j];
        floatx4 v = x[j];
#pragma unroll
        for (int e = 0; e < 4; ++e) {
            const float a = v[e] + b;
            v[e] = 0.5f * (a + sqrtf(fmaf(a, a, CURV2)));
        }
        x[j] = v;
    }

    rot_layer<4>(x, cs, sn);   // stride 1
    rot_layer<5>(x, cs, sn);   // stride 2
    rot_layer<6>(x, cs, sn);   // stride 4
    rot_layer<7>(x, cs, sn);   // stride 8

#pragma unroll
    for (int j = 0; j < 16; ++j) {
        const size_t off = (size_t)rout[j] * (size_t)B + (size_t)c0;
        *reinterpret_cast<floatx4*>(out + off) = x[j];
    }
}

// mark rows covered by idx_out
__global__ void mark_kernel(const int* __restrict__ idx_out,
                            int* __restrict__ mask, int N) {
    const int i = blockIdx.x * blockDim.x + threadIdx.x;
    if (i < N) mask[idx_out[i]] = 1;
}

// copy rows NOT covered by idx_out straight from data (out = data elsewhere)
__global__ __launch_bounds__(TPB) void copy_untouched(
    const float* __restrict__ data, float* __restrict__ out,
    const int* __restrict__ mask, int N, int B) {
    for (int row = blockIdx.x; row < N; row += gridDim.x) {
        if (mask[row]) continue;
        const floatx4* src = reinterpret_cast<const floatx4*>(data + (size_t)row * B);
        floatx4* dst = reinterpret_cast<floatx4*>(out + (size_t)row * B);
        for (int c = threadIdx.x; c < (B >> 2); c += blockDim.x)
            dst[c] = src[c];
    }
}

extern "C" void kernel_launch(void* const* d_in, const int* in_sizes, int n_in,
                              void* d_out, int out_size, void* d_ws, size_t ws_size,
                              hipStream_t stream) {
    const float* data       = (const float*)d_in[0];
    const float* angles     = (const float*)d_in[1];
    const float* biases     = (const float*)d_in[2];
    const int*   indices_in = (const int*)d_in[3];
    const int*   idx_out    = (const int*)d_in[4];
    float* out = (float*)d_out;

    const int N = in_sizes[3];          // 4096
    const int B = in_sizes[0] / N;      // 8192

    int* mask = (int*)d_ws;
    hipMemsetAsync(mask, 0, (size_t)N * sizeof(int), stream);
    mark_kernel<<<dim3((N + TPB - 1) / TPB), dim3(TPB), 0, stream>>>(idx_out, mask, N);

    dim3 grid(B / (TPB * CPT), N / COL_BLOCK);   // column tile fastest
    butterfly_kernel<<<grid, dim3(TPB), 0, stream>>>(
        data, angles, biases, indices_in, idx_out, out, N, B);

    copy_untouched<<<dim3(256), dim3(TPB), 0, stream>>>(data, out, mask, N, B);
}